// Round 7
// baseline (275.890 us; speedup 1.0000x reference)
//
#include <hip/hip_runtime.h>
#include <math.h>

#define B_DIM 4
#define F_DIM 512
#define T_DIM 2048
#define H_DIM 4
#define HF    128

typedef __attribute__((ext_vector_type(8))) short short8;
typedef __attribute__((ext_vector_type(4))) float floatx4;

// round-half-up bf16 (3 inst); RNE-vs-half-up delta <= 0.5 ulp, irrelevant at our threshold
__device__ __forceinline__ unsigned short f2bf(float f) {
    return (unsigned short)((__float_as_uint(f) + 0x8000u) >> 16);
}

// two floats -> packed bf16 pair: 2 adds + 1 v_perm_b32
__device__ __forceinline__ unsigned pkbf2(float a, float b) {
    const unsigned ua = __float_as_uint(a) + 0x8000u;
    const unsigned ub = __float_as_uint(b) + 0x8000u;
    return __builtin_amdgcn_perm(ub, ua, 0x07060302u);  // [ua.hi16 | ub.hi16]
}

__device__ __forceinline__ short8 pack8(const float* v) {
    union { unsigned u[4]; short8 s; } r;
    #pragma unroll
    for (int j = 0; j < 4; ++j) r.u[j] = pkbf2(v[2*j], v[2*j+1]);
    return r.s;
}

// ---------------- Kernel 0: prep ----------------
__global__ __launch_bounds__(256)
void prep_kernel(const float* __restrict__ x,
                 const float* __restrict__ Wq, const float* __restrict__ Wk,
                 const float* __restrict__ Wv,
                 unsigned short* __restrict__ xt,
                 unsigned short* __restrict__ Wqb, unsigned short* __restrict__ Wkb,
                 unsigned short* __restrict__ Wvb)
{
    const int tid = threadIdx.x;
    if (blockIdx.z < B_DIM) {
        const int b  = blockIdx.z;
        const int t0 = blockIdx.x * 64;
        const int f0 = blockIdx.y * 64;
        __shared__ float Ls[64][67];
        const float* __restrict__ xb = x + (size_t)b * F_DIM * T_DIM;
        #pragma unroll
        for (int it = 0; it < 4; ++it) {
            const int fr = (tid >> 4) + 16 * it;
            const int tc = (tid & 15) << 2;
            const float4 v = *(const float4*)(xb + (size_t)(f0 + fr) * T_DIM + t0 + tc);
            Ls[fr][tc+0] = v.x; Ls[fr][tc+1] = v.y; Ls[fr][tc+2] = v.z; Ls[fr][tc+3] = v.w;
        }
        __syncthreads();
        const int f8 = tid & 7;
        const int tb = tid >> 3;
        #pragma unroll
        for (int it2 = 0; it2 < 2; ++it2) {
            const int t = tb + 32 * it2;
            float v[8];
            #pragma unroll
            for (int j = 0; j < 8; ++j) v[j] = Ls[8*f8 + j][t];
            *(short8*)(xt + ((size_t)b * T_DIM + t0 + t) * F_DIM + f0 + 8*f8) = pack8(v);
        }
    } else {
        const int blockId = blockIdx.y * 32 + blockIdx.x;
        const int g0 = blockId * 256 + tid;
        const int perW = F_DIM * F_DIM / 8;
        for (int chunk = g0; chunk < 3 * perW; chunk += 65536) {
            const int wsel = chunk / perW;
            const int rem  = chunk - wsel * perW;
            const float* __restrict__ Ws = (wsel == 0) ? Wq : (wsel == 1) ? Wk : Wv;
            unsigned short* __restrict__ Wd = (wsel == 0) ? Wqb : (wsel == 1) ? Wkb : Wvb;
            float v[8];
            *(float4*)&v[0] = *(const float4*)(Ws + (size_t)rem * 8);
            *(float4*)&v[4] = *(const float4*)(Ws + (size_t)rem * 8 + 4);
            *(short8*)(Wd + (size_t)rem * 8) = pack8(v);
        }
    }
}

// ---------------- Kernel 1: merged QKV projection ----------------
// z<8: Q/K path (b=z>>1, which=z&1): C[t][fo], 128t x 64fo tiles, RoPE epilogue.
// z>=8: V^T path (b=z-8): A=Wv so D rows=fo, cols=t -> coalesced V^T store.
#define ASTR 72

__global__ __launch_bounds__(256)
void proj_kernel(const unsigned short* __restrict__ xt,
                 const unsigned short* __restrict__ Wqb,
                 const unsigned short* __restrict__ Wkb,
                 const unsigned short* __restrict__ Wvb,
                 const float* __restrict__ bq, const float* __restrict__ bk,
                 const float* __restrict__ bv,
                 unsigned short* __restrict__ Qb, unsigned short* __restrict__ Kb,
                 unsigned short* __restrict__ Vtb)
{
    __shared__ unsigned short As[128][ASTR];
    __shared__ unsigned short Bs[64][ASTR];

    const int tid  = threadIdx.x;
    const int w    = tid >> 6;
    const int lane = tid & 63;
    const int ln15 = lane & 15;
    const int quad = lane >> 4;

    const bool is_v = (blockIdx.z >= 8);
    int t0, fo0, b;
    const unsigned short *Asrc, *Bsrc;
    if (!is_v) {
        t0  = blockIdx.x * 128;
        fo0 = blockIdx.y * 64;
        b   = blockIdx.z >> 1;
        Asrc = xt + (size_t)b * T_DIM * F_DIM + (size_t)t0 * F_DIM;
        Bsrc = ((blockIdx.z & 1) ? Wkb : Wqb) + (size_t)fo0 * F_DIM;
    } else {
        const int idx = blockIdx.y * 16 + blockIdx.x;   // 0..127
        fo0 = (idx >> 5) * 128;
        t0  = (idx & 31) * 64;
        b   = blockIdx.z - 8;
        Asrc = Wvb + (size_t)fo0 * F_DIM;
        Bsrc = xt + (size_t)b * T_DIM * F_DIM + (size_t)t0 * F_DIM;
    }

    floatx4 acc[2][4];
    #pragma unroll
    for (int mi = 0; mi < 2; ++mi)
        #pragma unroll
        for (int nt = 0; nt < 4; ++nt) acc[mi][nt] = (floatx4){0.f,0.f,0.f,0.f};

    for (int f0 = 0; f0 < F_DIM; f0 += 64) {
        __syncthreads();
        #pragma unroll
        for (int it = 0; it < 4; ++it) {
            const int idx = tid + it * 256;
            const int r = idx >> 3, c = (idx & 7) * 8;
            *(short8*)&As[r][c] = *(const short8*)(Asrc + (size_t)r * F_DIM + f0 + c);
        }
        #pragma unroll
        for (int it = 0; it < 2; ++it) {
            const int idx = tid + it * 256;
            const int r = idx >> 3, c = (idx & 7) * 8;
            *(short8*)&Bs[r][c] = *(const short8*)(Bsrc + (size_t)r * F_DIM + f0 + c);
        }
        __syncthreads();
        #pragma unroll
        for (int ks = 0; ks < 2; ++ks) {
            short8 a[2], bb[4];
            a[0] = *(const short8*)&As[w*32      + ln15][ks*32 + quad*8];
            a[1] = *(const short8*)&As[w*32 + 16 + ln15][ks*32 + quad*8];
            #pragma unroll
            for (int nt = 0; nt < 4; ++nt)
                bb[nt] = *(const short8*)&Bs[16*nt + ln15][ks*32 + quad*8];
            #pragma unroll
            for (int mi = 0; mi < 2; ++mi)
                #pragma unroll
                for (int nt = 0; nt < 4; ++nt)
                    acc[mi][nt] = __builtin_amdgcn_mfma_f32_16x16x32_bf16(
                        a[mi], bb[nt], acc[mi][nt], 0, 0, 0);
        }
    }

    if (!is_v) {
        const int which = blockIdx.z & 1;
        const float* bias = which ? bk : bq;
        unsigned short* __restrict__ Out =
            (which ? Kb : Qb) + (size_t)b * T_DIM * F_DIM;
        const float oscale = which ? 1.0f : 0.0625f;   // fold 1/sqrt(F/2) into Q
        float bn[4];
        #pragma unroll
        for (int nt = 0; nt < 4; ++nt) bn[nt] = bias[fo0 + 16*nt + ln15];
        // 2^-(wi+4) built directly from exponent bits (wi = 16*pr + ln15)
        const float pw[2] = {
            __uint_as_float((unsigned)(123 - ln15) << 23),
            __uint_as_float((unsigned)(107 - ln15) << 23)
        };
        #pragma unroll
        for (int mi = 0; mi < 2; ++mi) {
            #pragma unroll
            for (int r = 0; r < 4; ++r) {
                const int t = t0 + w*32 + 16*mi + quad*4 + r;
                unsigned short* rowp = Out + (size_t)t * F_DIM + fo0;
                #pragma unroll
                for (int pr = 0; pr < 2; ++pr) {
                    const int wi = 16*pr + ln15;
                    const float re = acc[mi][pr  ][r] + bn[pr];
                    const float im = acc[mi][pr+2][r] + bn[pr+2];
                    const float u = (float)t * pw[pr];
                    float sn, cs;
                    __sincosf(u, &sn, &cs);
                    rowp[wi]      = f2bf((re * sn - im * cs) * oscale);
                    rowp[wi + 32] = f2bf((re * cs + im * sn) * oscale);
                }
            }
        }
    } else {
        #pragma unroll
        for (int mi = 0; mi < 2; ++mi) {
            #pragma unroll
            for (int r = 0; r < 4; ++r) {
                const int fo = fo0 + w*32 + 16*mi + quad*4 + r;
                const float bvv = bv[fo];
                unsigned short* rowp = Vtb + ((size_t)b * F_DIM + fo) * T_DIM + t0;
                #pragma unroll
                for (int nt = 0; nt < 4; ++nt)
                    rowp[16*nt + ln15] = f2bf(acc[mi][nt][r] + bvv);
            }
        }
    }
}

// ---------------- Kernel 2: S^T MFMA flash attention, no-max, split-K x2 ----
// 512 threads = 8 waves: half = w8>>2 owns k-range [half*1024, +1024);
// w = w8&3 owns q-rows [q0+16w, +16). p = exp(S) directly (scores bounded).
// K staged in LDS (XOR-swizzled, conflict-free); V frags read DIRECTLY from
// global (per-tile 16 KB window is L1-resident; splits traffic across the
// vmem pipe instead of doubling the LDS pipe load — R6 was LDS-pipe-bound).
__global__ __launch_bounds__(512, 2)
void attn_kernel(const unsigned short* __restrict__ Qb,
                 const unsigned short* __restrict__ Kb,
                 const unsigned short* __restrict__ Vtb,
                 const float* __restrict__ x,
                 const float* __restrict__ s2g,
                 float* __restrict__ out)
{
    __shared__ unsigned short smem[2][9216];   // K tiles (8192 used/half) + combine overlay

    const int tid  = threadIdx.x;
    const int w8   = tid >> 6;
    const int half = w8 >> 2;
    const int w    = w8 & 3;
    const int lane = tid & 63;
    const int ln15 = lane & 15;
    const int quad = lane >> 4;
    const int t256 = tid & 255;

    const int q0 = blockIdx.x * 64;
    const int h  = blockIdx.y;
    const int b  = blockIdx.z;
    const int kbase = half << 10;   // 0 or 1024

    unsigned short* __restrict__ Ks = &smem[half][0];     // 64 x 128 (swizzled)

    const unsigned short* __restrict__ Qg =
        Qb + ((size_t)b * T_DIM + q0 + w * 16) * F_DIM + h * HF;
    const unsigned short* __restrict__ Kg =
        Kb + (size_t)b * T_DIM * F_DIM + h * HF;
    const unsigned short* __restrict__ Vg =
        Vtb + ((size_t)b * F_DIM + h * HF) * T_DIM;

    // Q B-frags (resident): B[k=feat][n=q=ln15]
    short8 qa[4];
    #pragma unroll
    for (int c = 0; c < 4; ++c)
        qa[c] = *(const short8*)(Qg + (size_t)ln15 * F_DIM + quad * 8 + 32 * c);

    floatx4 O1t[8], O2t[8];
    #pragma unroll
    for (int ft = 0; ft < 8; ++ft) {
        O1t[ft] = (floatx4){0.f, 0.f, 0.f, 0.f};
        O2t[ft] = (floatx4){0.f, 0.f, 0.f, 0.f};
    }
    float l1 = 0.f, l2 = 0.f;

    short8 kpre[4];
    #pragma unroll
    for (int it = 0; it < 4; ++it) {
        const int idx = t256 + it * 256;
        kpre[it] = *(const short8*)(Kg + (size_t)(kbase + (idx >> 4)) * F_DIM + (idx & 15) * 8);
    }

    for (int k0 = 0; k0 < 1024; k0 += 64) {
        __syncthreads();   // all waves done reading previous K tile
        #pragma unroll
        for (int it = 0; it < 4; ++it) {
            const int idx = t256 + it * 256;
            const int r = idx >> 4, c = idx & 15;
            // row perm so P^T C-regs align with PV B-frag slots (verified R4)
            const int rp = (r & 32) | ((r & 4) << 2) | ((r & 24) >> 1) | (r & 3);
            *(short8*)&Ks[rp * 128 + (c ^ (rp & 15)) * 8] = kpre[it];
        }
        __syncthreads();   // tile visible

        if (k0 + 64 < 1024) {   // prefetch next K tile
            #pragma unroll
            for (int it = 0; it < 4; ++it) {
                const int idx = t256 + it * 256;
                kpre[it] = *(const short8*)(Kg + (size_t)(kbase + k0 + 64 + (idx >> 4)) * F_DIM + (idx & 15) * 8);
            }
        }

        // ---- scores S^T[k][q] ----
        floatx4 S1t[4], S2t[4];
        #pragma unroll
        for (int t = 0; t < 4; ++t) {
            const unsigned short* krow = &Ks[(16 * t + ln15) * 128];
            const short8 k0f = *(const short8*)(krow + ((quad     ) ^ ln15) * 8);
            const short8 k1f = *(const short8*)(krow + ((quad +  4) ^ ln15) * 8);
            const short8 k2f = *(const short8*)(krow + ((quad +  8) ^ ln15) * 8);
            const short8 k3f = *(const short8*)(krow + ((quad + 12) ^ ln15) * 8);
            floatx4 z = (floatx4){0.f, 0.f, 0.f, 0.f};
            floatx4 s = __builtin_amdgcn_mfma_f32_16x16x32_bf16(k0f, qa[0], z, 0, 0, 0);
            S1t[t]    = __builtin_amdgcn_mfma_f32_16x16x32_bf16(k1f, qa[1], s, 0, 0, 0);
            floatx4 u = __builtin_amdgcn_mfma_f32_16x16x32_bf16(k2f, qa[2], z, 0, 0, 0);
            S2t[t]    = __builtin_amdgcn_mfma_f32_16x16x32_bf16(k3f, qa[3], u, 0, 0, 0);
        }

        // ---- no-max softmax numerators ----
        float e1[16], e2[16];
        #pragma unroll
        for (int t = 0; t < 4; ++t)
            #pragma unroll
            for (int r = 0; r < 4; ++r) {
                e1[4*t + r] = __expf(S1t[t][r]);
                e2[4*t + r] = __expf(S2t[t][r]);
            }
        #pragma unroll
        for (int i = 0; i < 16; ++i) { l1 += e1[i]; l2 += e2[i]; }

        short8 p1f[2], p2f[2];
        p1f[0] = pack8(&e1[0]);  p1f[1] = pack8(&e1[8]);
        p2f[0] = pack8(&e2[0]);  p2f[1] = pack8(&e2[8]);

        // ---- PV: O^T += V^T . P^T ; V frags straight from global (L1-hot) ----
        #pragma unroll
        for (int p = 0; p < 2; ++p) {
            #pragma unroll
            for (int ft = 0; ft < 8; ++ft) {
                const short8 va = *(const short8*)
                    (Vg + (size_t)(16*ft + ln15) * T_DIM + kbase + k0 + 32*p + quad*8);
                O1t[ft] = __builtin_amdgcn_mfma_f32_16x16x32_bf16(va, p1f[p], O1t[ft], 0, 0, 0);
                O2t[ft] = __builtin_amdgcn_mfma_f32_16x16x32_bf16(va, p2f[p], O2t[ft], 0, 0, 0);
            }
        }
    }

    // ---- reductions: intra-wave l across quads, then cross-half via LDS ----
    l1 += __shfl_xor(l1, 16); l1 += __shfl_xor(l1, 32);
    l2 += __shfl_xor(l2, 16); l2 += __shfl_xor(l2, 32);

    float* comb = (float*)&smem[0][0];   // overlays both halves' K tiles (36 KB)
    __syncthreads();   // all compute done, smem reusable
    if (half == 1) {
        if (quad == 0) { comb[w*16 + ln15] = l1; comb[64 + w*16 + ln15] = l2; }
        #pragma unroll
        for (int ft = 0; ft < 8; ++ft)
            #pragma unroll
            for (int r = 0; r < 4; ++r)
                comb[128 + (ft*4 + r) * 256 + w*64 + lane] = O1t[ft][r];
    }
    __syncthreads();
    if (half == 0) {
        l1 += comb[w*16 + ln15];
        l2 += comb[64 + w*16 + ln15];
        #pragma unroll
        for (int ft = 0; ft < 8; ++ft)
            #pragma unroll
            for (int r = 0; r < 4; ++r)
                O1t[ft][r] += comb[128 + (ft*4 + r) * 256 + w*64 + lane];
    }
    __syncthreads();
    if (half == 1) {
        #pragma unroll
        for (int ft = 0; ft < 8; ++ft)
            #pragma unroll
            for (int r = 0; r < 4; ++r)
                comb[128 + (ft*4 + r) * 256 + w*64 + lane] = O2t[ft][r];
    }
    __syncthreads();
    if (half == 0) {
        #pragma unroll
        for (int ft = 0; ft < 8; ++ft)
            #pragma unroll
            for (int r = 0; r < 4; ++r)
                O2t[ft][r] += comb[128 + (ft*4 + r) * 256 + w*64 + lane];

        // ---- epilogue: out = x + O1/l1 - s2*O2/l2, layout [B][F][T] ----
        const float s2h = s2g[h];
        const float i1 = 1.f / l1;
        const float i2 = s2h / l2;
        const size_t obase = (size_t)b * F_DIM * T_DIM;
        const int f0 = h * HF;
        const int t = q0 + w * 16 + ln15;
        #pragma unroll
        for (int ft = 0; ft < 8; ++ft) {
            #pragma unroll
            for (int r = 0; r < 4; ++r) {
                const int feat = 16*ft + 4*quad + r;
                const size_t idx = obase + (size_t)(f0 + feat) * T_DIM + t;
                out[idx] = x[idx] + O1t[ft][r] * i1 - O2t[ft][r] * i2;
            }
        }
    }
}

extern "C" void kernel_launch(void* const* d_in, const int* in_sizes, int n_in,
                              void* d_out, int out_size, void* d_ws, size_t ws_size,
                              hipStream_t stream)
{
    const float* x  = (const float*)d_in[0];
    const float* Wq = (const float*)d_in[1];
    const float* bq = (const float*)d_in[2];
    const float* Wk = (const float*)d_in[3];
    const float* bk = (const float*)d_in[4];
    const float* Wv = (const float*)d_in[5];
    const float* bv = (const float*)d_in[6];
    const float* s2 = (const float*)d_in[7];
    float* out = (float*)d_out;

    const size_t per = (size_t)B_DIM * T_DIM * F_DIM;
    const size_t wsz = (size_t)F_DIM * F_DIM;
    unsigned short* xt  = (unsigned short*)d_ws;
    unsigned short* Wqb = xt + per;
    unsigned short* Wkb = Wqb + wsz;
    unsigned short* Wvb = Wkb + wsz;
    unsigned short* Qb  = Wvb + wsz;
    unsigned short* Kb  = Qb + per;
    unsigned short* Vtb = Kb + per;

    hipLaunchKernelGGL(prep_kernel, dim3(32, 8, 5), dim3(256), 0, stream,
                       x, Wq, Wk, Wv, xt, Wqb, Wkb, Wvb);

    hipLaunchKernelGGL(proj_kernel, dim3(16, 8, 12), dim3(256), 0, stream,
                       xt, Wqb, Wkb, Wvb, bq, bk, bv, Qb, Kb, Vtb);

    hipLaunchKernelGGL(attn_kernel, dim3(32, 4, 4), dim3(512), 0, stream,
                       Qb, Kb, Vtb, x, s2, out);
}

// Round 8
// 241.205 us; speedup vs baseline: 1.1438x; 1.1438x over previous
//
#include <hip/hip_runtime.h>
#include <math.h>

#define B_DIM 4
#define F_DIM 512
#define T_DIM 2048
#define H_DIM 4
#define HF    128

typedef __attribute__((ext_vector_type(8))) short short8;
typedef __attribute__((ext_vector_type(4))) float floatx4;

// round-half-up bf16 (3 inst)
__device__ __forceinline__ unsigned short f2bf(float f) {
    return (unsigned short)((__float_as_uint(f) + 0x8000u) >> 16);
}

// two floats -> packed bf16 pair: 2 adds + 1 v_perm_b32
__device__ __forceinline__ unsigned pkbf2(float a, float b) {
    const unsigned ua = __float_as_uint(a) + 0x8000u;
    const unsigned ub = __float_as_uint(b) + 0x8000u;
    return __builtin_amdgcn_perm(ub, ua, 0x07060302u);  // [ua.hi16 | ub.hi16]
}

__device__ __forceinline__ short8 pack8(const float* v) {
    union { unsigned u[4]; short8 s; } r;
    #pragma unroll
    for (int j = 0; j < 4; ++j) r.u[j] = pkbf2(v[2*j], v[2*j+1]);
    return r.s;
}

// ---------------- Kernel 0: prep ----------------
__global__ __launch_bounds__(256)
void prep_kernel(const float* __restrict__ x,
                 const float* __restrict__ Wq, const float* __restrict__ Wk,
                 const float* __restrict__ Wv,
                 unsigned short* __restrict__ xt,
                 unsigned short* __restrict__ Wqb, unsigned short* __restrict__ Wkb,
                 unsigned short* __restrict__ Wvb)
{
    const int tid = threadIdx.x;
    if (blockIdx.z < B_DIM) {
        const int b  = blockIdx.z;
        const int t0 = blockIdx.x * 64;
        const int f0 = blockIdx.y * 64;
        __shared__ float Ls[64][67];
        const float* __restrict__ xb = x + (size_t)b * F_DIM * T_DIM;
        #pragma unroll
        for (int it = 0; it < 4; ++it) {
            const int fr = (tid >> 4) + 16 * it;
            const int tc = (tid & 15) << 2;
            const float4 v = *(const float4*)(xb + (size_t)(f0 + fr) * T_DIM + t0 + tc);
            Ls[fr][tc+0] = v.x; Ls[fr][tc+1] = v.y; Ls[fr][tc+2] = v.z; Ls[fr][tc+3] = v.w;
        }
        __syncthreads();
        const int f8 = tid & 7;
        const int tb = tid >> 3;
        #pragma unroll
        for (int it2 = 0; it2 < 2; ++it2) {
            const int t = tb + 32 * it2;
            float v[8];
            #pragma unroll
            for (int j = 0; j < 8; ++j) v[j] = Ls[8*f8 + j][t];
            *(short8*)(xt + ((size_t)b * T_DIM + t0 + t) * F_DIM + f0 + 8*f8) = pack8(v);
        }
    } else {
        const int blockId = blockIdx.y * 32 + blockIdx.x;
        const int g0 = blockId * 256 + tid;
        const int perW = F_DIM * F_DIM / 8;
        for (int chunk = g0; chunk < 3 * perW; chunk += 65536) {
            const int wsel = chunk / perW;
            const int rem  = chunk - wsel * perW;
            const float* __restrict__ Ws = (wsel == 0) ? Wq : (wsel == 1) ? Wk : Wv;
            unsigned short* __restrict__ Wd = (wsel == 0) ? Wqb : (wsel == 1) ? Wkb : Wvb;
            float v[8];
            *(float4*)&v[0] = *(const float4*)(Ws + (size_t)rem * 8);
            *(float4*)&v[4] = *(const float4*)(Ws + (size_t)rem * 8 + 4);
            *(short8*)(Wd + (size_t)rem * 8) = pack8(v);
        }
    }
}

// ---------------- Kernel 1: merged QKV projection ----------------
#define ASTR 72

__global__ __launch_bounds__(256)
void proj_kernel(const unsigned short* __restrict__ xt,
                 const unsigned short* __restrict__ Wqb,
                 const unsigned short* __restrict__ Wkb,
                 const unsigned short* __restrict__ Wvb,
                 const float* __restrict__ bq, const float* __restrict__ bk,
                 const float* __restrict__ bv,
                 unsigned short* __restrict__ Qb, unsigned short* __restrict__ Kb,
                 unsigned short* __restrict__ Vtb)
{
    __shared__ unsigned short As[128][ASTR];
    __shared__ unsigned short Bs[64][ASTR];

    const int tid  = threadIdx.x;
    const int w    = tid >> 6;
    const int lane = tid & 63;
    const int ln15 = lane & 15;
    const int quad = lane >> 4;

    const bool is_v = (blockIdx.z >= 8);
    int t0, fo0, b;
    const unsigned short *Asrc, *Bsrc;
    if (!is_v) {
        t0  = blockIdx.x * 128;
        fo0 = blockIdx.y * 64;
        b   = blockIdx.z >> 1;
        Asrc = xt + (size_t)b * T_DIM * F_DIM + (size_t)t0 * F_DIM;
        Bsrc = ((blockIdx.z & 1) ? Wkb : Wqb) + (size_t)fo0 * F_DIM;
    } else {
        const int idx = blockIdx.y * 16 + blockIdx.x;   // 0..127
        fo0 = (idx >> 5) * 128;
        t0  = (idx & 31) * 64;
        b   = blockIdx.z - 8;
        Asrc = Wvb + (size_t)fo0 * F_DIM;
        Bsrc = xt + (size_t)b * T_DIM * F_DIM + (size_t)t0 * F_DIM;
    }

    floatx4 acc[2][4];
    #pragma unroll
    for (int mi = 0; mi < 2; ++mi)
        #pragma unroll
        for (int nt = 0; nt < 4; ++nt) acc[mi][nt] = (floatx4){0.f,0.f,0.f,0.f};

    for (int f0 = 0; f0 < F_DIM; f0 += 64) {
        __syncthreads();
        #pragma unroll
        for (int it = 0; it < 4; ++it) {
            const int idx = tid + it * 256;
            const int r = idx >> 3, c = (idx & 7) * 8;
            *(short8*)&As[r][c] = *(const short8*)(Asrc + (size_t)r * F_DIM + f0 + c);
        }
        #pragma unroll
        for (int it = 0; it < 2; ++it) {
            const int idx = tid + it * 256;
            const int r = idx >> 3, c = (idx & 7) * 8;
            *(short8*)&Bs[r][c] = *(const short8*)(Bsrc + (size_t)r * F_DIM + f0 + c);
        }
        __syncthreads();
        #pragma unroll
        for (int ks = 0; ks < 2; ++ks) {
            short8 a[2], bb[4];
            a[0] = *(const short8*)&As[w*32      + ln15][ks*32 + quad*8];
            a[1] = *(const short8*)&As[w*32 + 16 + ln15][ks*32 + quad*8];
            #pragma unroll
            for (int nt = 0; nt < 4; ++nt)
                bb[nt] = *(const short8*)&Bs[16*nt + ln15][ks*32 + quad*8];
            #pragma unroll
            for (int mi = 0; mi < 2; ++mi)
                #pragma unroll
                for (int nt = 0; nt < 4; ++nt)
                    acc[mi][nt] = __builtin_amdgcn_mfma_f32_16x16x32_bf16(
                        a[mi], bb[nt], acc[mi][nt], 0, 0, 0);
        }
    }

    if (!is_v) {
        const int which = blockIdx.z & 1;
        const float* bias = which ? bk : bq;
        unsigned short* __restrict__ Out =
            (which ? Kb : Qb) + (size_t)b * T_DIM * F_DIM;
        const float oscale = which ? 1.0f : 0.0625f;   // fold 1/sqrt(F/2) into Q
        float bn[4];
        #pragma unroll
        for (int nt = 0; nt < 4; ++nt) bn[nt] = bias[fo0 + 16*nt + ln15];
        const float pw[2] = {
            __uint_as_float((unsigned)(123 - ln15) << 23),   // 2^-(ln15+4)
            __uint_as_float((unsigned)(107 - ln15) << 23)    // 2^-(ln15+20)
        };
        #pragma unroll
        for (int mi = 0; mi < 2; ++mi) {
            #pragma unroll
            for (int r = 0; r < 4; ++r) {
                const int t = t0 + w*32 + 16*mi + quad*4 + r;
                unsigned short* rowp = Out + (size_t)t * F_DIM + fo0;
                #pragma unroll
                for (int pr = 0; pr < 2; ++pr) {
                    const int wi = 16*pr + ln15;
                    const float re = acc[mi][pr  ][r] + bn[pr];
                    const float im = acc[mi][pr+2][r] + bn[pr+2];
                    const float u = (float)t * pw[pr];
                    float sn, cs;
                    __sincosf(u, &sn, &cs);
                    rowp[wi]      = f2bf((re * sn - im * cs) * oscale);
                    rowp[wi + 32] = f2bf((re * cs + im * sn) * oscale);
                }
            }
        }
    } else {
        #pragma unroll
        for (int mi = 0; mi < 2; ++mi) {
            #pragma unroll
            for (int r = 0; r < 4; ++r) {
                const int fo = fo0 + w*32 + 16*mi + quad*4 + r;
                const float bvv = bv[fo];
                unsigned short* rowp = Vtb + ((size_t)b * F_DIM + fo) * T_DIM + t0;
                #pragma unroll
                for (int nt = 0; nt < 4; ++nt)
                    rowp[16*nt + ln15] = f2bf(acc[mi][nt][r] + bvv);
            }
        }
    }
}

// ---------------- Kernel 2: S^T MFMA flash attention --------------------
// R6 structure (K+V in LDS, XOR swizzle, 0 conflicts) + 32 q-rows per wave:
// each K-frag LDS read feeds 2 score MFMAs, each V-frag read feeds 4 PV MFMAs
// -> LDS-pipe load per unit work halves (R6 was LDS-pipe-bound at ~51 us).
// 512 thr = 8 waves: half=w8>>2 owns k-range [half*1024,+1024); w=w8&3 owns
// q-rows [q0+32w, +32) as two 16-row B-halves qh. Two-phase softmax (S1 fully
// retired before S2) keeps transient regs low; V staged directly (no vpre).
__global__ __launch_bounds__(512, 2)
void attn_kernel(const unsigned short* __restrict__ Qb,
                 const unsigned short* __restrict__ Kb,
                 const unsigned short* __restrict__ Vtb,
                 const float* __restrict__ x,
                 const float* __restrict__ s2g,
                 float* __restrict__ out)
{
    __shared__ unsigned short smem[2][16384];   // [half][K 8192 | V 8192] = 64 KB

    const int tid  = threadIdx.x;
    const int w8   = tid >> 6;
    const int half = w8 >> 2;
    const int w    = w8 & 3;
    const int lane = tid & 63;
    const int ln15 = lane & 15;
    const int quad = lane >> 4;
    const int t256 = tid & 255;

    const int q0 = blockIdx.x * 128;
    const int hd = blockIdx.y;
    const int b  = blockIdx.z;
    const int kbase = half << 10;   // 0 or 1024

    unsigned short* __restrict__ Ks = &smem[half][0];     // 64 x 128 (perm+swizzle)
    unsigned short* __restrict__ Vs = &smem[half][8192];  // 128 x 64 (swizzle)

    const unsigned short* __restrict__ Qg =
        Qb + ((size_t)b * T_DIM + q0 + w * 32) * F_DIM + hd * HF;
    const unsigned short* __restrict__ Kg =
        Kb + (size_t)b * T_DIM * F_DIM + hd * HF;
    const unsigned short* __restrict__ Vg =
        Vtb + ((size_t)b * F_DIM + hd * HF) * T_DIM;

    // Q B-frags (resident): qa[qh][c], B[k=feat][n=q=ln15]
    short8 qa[2][4];
    #pragma unroll
    for (int qh = 0; qh < 2; ++qh)
        #pragma unroll
        for (int c = 0; c < 4; ++c)
            qa[qh][c] = *(const short8*)(Qg + (size_t)(16*qh + ln15) * F_DIM + quad * 8 + 32 * c);

    floatx4 O1t[2][8], O2t[2][8];
    #pragma unroll
    for (int qh = 0; qh < 2; ++qh)
        #pragma unroll
        for (int ft = 0; ft < 8; ++ft) {
            O1t[qh][ft] = (floatx4){0.f, 0.f, 0.f, 0.f};
            O2t[qh][ft] = (floatx4){0.f, 0.f, 0.f, 0.f};
        }
    float l1[2] = {0.f, 0.f}, l2[2] = {0.f, 0.f};

    short8 kpre[4];
    #pragma unroll
    for (int it = 0; it < 4; ++it) {
        const int idx = t256 + it * 256;
        kpre[it] = *(const short8*)(Kg + (size_t)(kbase + (idx >> 4)) * F_DIM + (idx & 15) * 8);
    }

    for (int k0 = 0; k0 < 1024; k0 += 64) {
        __syncthreads();   // all waves done reading previous tiles
        #pragma unroll
        for (int it = 0; it < 4; ++it) {
            const int idx = t256 + it * 256;
            const int r = idx >> 4, c = idx & 15;
            // row perm so P^T C-regs align with PV B-frag slots (verified R4-R6)
            const int rp = (r & 32) | ((r & 4) << 2) | ((r & 24) >> 1) | (r & 3);
            *(short8*)&Ks[rp * 128 + (c ^ (rp & 15)) * 8] = kpre[it];
        }
        #pragma unroll
        for (int it = 0; it < 4; ++it) {
            const int idx = t256 + it * 256;
            const int r = idx >> 3, c = idx & 7;
            *(short8*)&Vs[r * 64 + (c ^ (r & 7)) * 8] =
                *(const short8*)(Vg + (size_t)r * T_DIM + kbase + k0 + c * 8);
        }
        __syncthreads();   // tiles visible

        if (k0 + 64 < 1024) {   // prefetch next K tile across the compute phase
            #pragma unroll
            for (int it = 0; it < 4; ++it) {
                const int idx = t256 + it * 256;
                kpre[it] = *(const short8*)(Kg + (size_t)(kbase + k0 + 64 + (idx >> 4)) * F_DIM + (idx & 15) * 8);
            }
        }

        short8 p1f[2][2], p2f[2][2];

        // ---- phase 1: S1 (feats 0..63) -> p1f ----
        {
            floatx4 S[4][2];
            #pragma unroll
            for (int t = 0; t < 4; ++t) {
                const unsigned short* krow = &Ks[(16 * t + ln15) * 128];
                const short8 k0f = *(const short8*)(krow + ((quad    ) ^ ln15) * 8);
                const short8 k1f = *(const short8*)(krow + ((quad + 4) ^ ln15) * 8);
                #pragma unroll
                for (int qh = 0; qh < 2; ++qh) {
                    floatx4 z = (floatx4){0.f, 0.f, 0.f, 0.f};
                    floatx4 s = __builtin_amdgcn_mfma_f32_16x16x32_bf16(k0f, qa[qh][0], z, 0, 0, 0);
                    S[t][qh]  = __builtin_amdgcn_mfma_f32_16x16x32_bf16(k1f, qa[qh][1], s, 0, 0, 0);
                }
            }
            #pragma unroll
            for (int qh = 0; qh < 2; ++qh) {
                float e[16], sm = 0.f;
                #pragma unroll
                for (int t = 0; t < 4; ++t)
                    #pragma unroll
                    for (int r = 0; r < 4; ++r) {
                        const float v = __expf(S[t][qh][r]);
                        e[4*t + r] = v; sm += v;
                    }
                l1[qh] += sm;
                p1f[qh][0] = pack8(&e[0]);
                p1f[qh][1] = pack8(&e[8]);
            }
        }

        // ---- phase 2: S2 (feats 64..127) -> p2f ----
        {
            floatx4 S[4][2];
            #pragma unroll
            for (int t = 0; t < 4; ++t) {
                const unsigned short* krow = &Ks[(16 * t + ln15) * 128];
                const short8 k2f = *(const short8*)(krow + ((quad +  8) ^ ln15) * 8);
                const short8 k3f = *(const short8*)(krow + ((quad + 12) ^ ln15) * 8);
                #pragma unroll
                for (int qh = 0; qh < 2; ++qh) {
                    floatx4 z = (floatx4){0.f, 0.f, 0.f, 0.f};
                    floatx4 s = __builtin_amdgcn_mfma_f32_16x16x32_bf16(k2f, qa[qh][2], z, 0, 0, 0);
                    S[t][qh]  = __builtin_amdgcn_mfma_f32_16x16x32_bf16(k3f, qa[qh][3], s, 0, 0, 0);
                }
            }
            #pragma unroll
            for (int qh = 0; qh < 2; ++qh) {
                float e[16], sm = 0.f;
                #pragma unroll
                for (int t = 0; t < 4; ++t)
                    #pragma unroll
                    for (int r = 0; r < 4; ++r) {
                        const float v = __expf(S[t][qh][r]);
                        e[4*t + r] = v; sm += v;
                    }
                l2[qh] += sm;
                p2f[qh][0] = pack8(&e[0]);
                p2f[qh][1] = pack8(&e[8]);
            }
        }

        // ---- PV: each V-frag read feeds 4 MFMAs ----
        #pragma unroll
        for (int p = 0; p < 2; ++p) {
            #pragma unroll
            for (int ft = 0; ft < 8; ++ft) {
                const short8 va = *(const short8*)
                    (&Vs[(16*ft + ln15) * 64 + (((4*p + quad) ^ (ln15 & 7))) * 8]);
                #pragma unroll
                for (int qh = 0; qh < 2; ++qh) {
                    O1t[qh][ft] = __builtin_amdgcn_mfma_f32_16x16x32_bf16(va, p1f[qh][p], O1t[qh][ft], 0, 0, 0);
                    O2t[qh][ft] = __builtin_amdgcn_mfma_f32_16x16x32_bf16(va, p2f[qh][p], O2t[qh][ft], 0, 0, 0);
                }
            }
        }
    }

    // ---- l: reduce across quads (lane holds quad-striped kcols) ----
    #pragma unroll
    for (int qh = 0; qh < 2; ++qh) {
        l1[qh] += __shfl_xor(l1[qh], 16); l1[qh] += __shfl_xor(l1[qh], 32);
        l2[qh] += __shfl_xor(l2[qh], 16); l2[qh] += __shfl_xor(l2[qh], 32);
    }

    // ---- cross-half combine: l round, then O1 round, then O2 round ----
    float* comb = (float*)&smem[0][0];   // full 64 KB = 16384 floats
    __syncthreads();
    if (half == 1 && quad == 0) {
        #pragma unroll
        for (int qh = 0; qh < 2; ++qh) {
            comb[      qh*64 + w*16 + ln15] = l1[qh];
            comb[128 + qh*64 + w*16 + ln15] = l2[qh];
        }
    }
    __syncthreads();
    if (half == 0) {
        #pragma unroll
        for (int qh = 0; qh < 2; ++qh) {
            l1[qh] += comb[      qh*64 + w*16 + ln15];
            l2[qh] += comb[128 + qh*64 + w*16 + ln15];
        }
    }
    __syncthreads();
    if (half == 1) {
        #pragma unroll
        for (int qh = 0; qh < 2; ++qh)
            #pragma unroll
            for (int ft = 0; ft < 8; ++ft)
                #pragma unroll
                for (int r = 0; r < 4; ++r)
                    comb[(((qh*8 + ft)*4 + r) << 8) + w*64 + lane] = O1t[qh][ft][r];
    }
    __syncthreads();
    if (half == 0) {
        #pragma unroll
        for (int qh = 0; qh < 2; ++qh)
            #pragma unroll
            for (int ft = 0; ft < 8; ++ft)
                #pragma unroll
                for (int r = 0; r < 4; ++r)
                    O1t[qh][ft][r] += comb[(((qh*8 + ft)*4 + r) << 8) + w*64 + lane];
    }
    __syncthreads();
    if (half == 1) {
        #pragma unroll
        for (int qh = 0; qh < 2; ++qh)
            #pragma unroll
            for (int ft = 0; ft < 8; ++ft)
                #pragma unroll
                for (int r = 0; r < 4; ++r)
                    comb[(((qh*8 + ft)*4 + r) << 8) + w*64 + lane] = O2t[qh][ft][r];
    }
    __syncthreads();
    if (half == 0) {
        #pragma unroll
        for (int qh = 0; qh < 2; ++qh)
            #pragma unroll
            for (int ft = 0; ft < 8; ++ft)
                #pragma unroll
                for (int r = 0; r < 4; ++r)
                    O2t[qh][ft][r] += comb[(((qh*8 + ft)*4 + r) << 8) + w*64 + lane];

        // ---- epilogue: out = x + O1/l1 - s2*O2/l2, layout [B][F][T] ----
        const float s2h = s2g[hd];
        float i1[2], i2[2];
        #pragma unroll
        for (int qh = 0; qh < 2; ++qh) { i1[qh] = 1.f / l1[qh]; i2[qh] = s2h / l2[qh]; }
        const size_t obase = (size_t)b * F_DIM * T_DIM;
        const int f0 = hd * HF;
        #pragma unroll
        for (int qh = 0; qh < 2; ++qh) {
            const int t = q0 + w * 32 + 16*qh + ln15;
            #pragma unroll
            for (int ft = 0; ft < 8; ++ft) {
                #pragma unroll
                for (int r = 0; r < 4; ++r) {
                    const int feat = 16*ft + 4*quad + r;
                    const size_t idx = obase + (size_t)(f0 + feat) * T_DIM + t;
                    out[idx] = x[idx] + O1t[qh][ft][r] * i1[qh] - O2t[qh][ft][r] * i2[qh];
                }
            }
        }
    }
}

extern "C" void kernel_launch(void* const* d_in, const int* in_sizes, int n_in,
                              void* d_out, int out_size, void* d_ws, size_t ws_size,
                              hipStream_t stream)
{
    const float* x  = (const float*)d_in[0];
    const float* Wq = (const float*)d_in[1];
    const float* bq = (const float*)d_in[2];
    const float* Wk = (const float*)d_in[3];
    const float* bk = (const float*)d_in[4];
    const float* Wv = (const float*)d_in[5];
    const float* bv = (const float*)d_in[6];
    const float* s2 = (const float*)d_in[7];
    float* out = (float*)d_out;

    const size_t per = (size_t)B_DIM * T_DIM * F_DIM;
    const size_t wsz = (size_t)F_DIM * F_DIM;
    unsigned short* xt  = (unsigned short*)d_ws;
    unsigned short* Wqb = xt + per;
    unsigned short* Wkb = Wqb + wsz;
    unsigned short* Wvb = Wkb + wsz;
    unsigned short* Qb  = Wvb + wsz;
    unsigned short* Kb  = Qb + per;
    unsigned short* Vtb = Kb + per;

    hipLaunchKernelGGL(prep_kernel, dim3(32, 8, 5), dim3(256), 0, stream,
                       x, Wq, Wk, Wv, xt, Wqb, Wkb, Wvb);

    hipLaunchKernelGGL(proj_kernel, dim3(16, 8, 12), dim3(256), 0, stream,
                       xt, Wqb, Wkb, Wvb, bq, bk, bv, Qb, Kb, Vtb);

    hipLaunchKernelGGL(attn_kernel, dim3(16, 4, 4), dim3(512), 0, stream,
                       Qb, Kb, Vtb, x, s2, out);
}

// Round 9
// 173.422 us; speedup vs baseline: 1.5909x; 1.3909x over previous
//
#include <hip/hip_runtime.h>
#include <math.h>

#define B_DIM 4
#define F_DIM 512
#define T_DIM 2048
#define H_DIM 4
#define HF    128

typedef __attribute__((ext_vector_type(8))) short short8;
typedef __attribute__((ext_vector_type(4))) float floatx4;

// round-half-up bf16 (2 inst)
__device__ __forceinline__ unsigned short f2bf(float f) {
    return (unsigned short)((__float_as_uint(f) + 0x8000u) >> 16);
}

// two floats -> packed bf16 pair: 2 adds + 1 v_perm_b32
__device__ __forceinline__ unsigned pkbf2(float a, float b) {
    const unsigned ua = __float_as_uint(a) + 0x8000u;
    const unsigned ub = __float_as_uint(b) + 0x8000u;
    return __builtin_amdgcn_perm(ub, ua, 0x07060302u);  // [ua.hi16 | ub.hi16]
}

__device__ __forceinline__ short8 pack8(const float* v) {
    union { unsigned u[4]; short8 s; } r;
    #pragma unroll
    for (int j = 0; j < 4; ++j) r.u[j] = pkbf2(v[2*j], v[2*j+1]);
    return r.s;
}

// ---------------- Kernel 0: prep ----------------
__global__ __launch_bounds__(256)
void prep_kernel(const float* __restrict__ x,
                 const float* __restrict__ Wq, const float* __restrict__ Wk,
                 const float* __restrict__ Wv,
                 unsigned short* __restrict__ xt,
                 unsigned short* __restrict__ Wqb, unsigned short* __restrict__ Wkb,
                 unsigned short* __restrict__ Wvb)
{
    const int tid = threadIdx.x;
    if (blockIdx.z < B_DIM) {
        const int b  = blockIdx.z;
        const int t0 = blockIdx.x * 64;
        const int f0 = blockIdx.y * 64;
        __shared__ float Ls[64][67];
        const float* __restrict__ xb = x + (size_t)b * F_DIM * T_DIM;
        #pragma unroll
        for (int it = 0; it < 4; ++it) {
            const int fr = (tid >> 4) + 16 * it;
            const int tc = (tid & 15) << 2;
            const float4 v = *(const float4*)(xb + (size_t)(f0 + fr) * T_DIM + t0 + tc);
            Ls[fr][tc+0] = v.x; Ls[fr][tc+1] = v.y; Ls[fr][tc+2] = v.z; Ls[fr][tc+3] = v.w;
        }
        __syncthreads();
        const int f8 = tid & 7;
        const int tb = tid >> 3;
        #pragma unroll
        for (int it2 = 0; it2 < 2; ++it2) {
            const int t = tb + 32 * it2;
            float v[8];
            #pragma unroll
            for (int j = 0; j < 8; ++j) v[j] = Ls[8*f8 + j][t];
            *(short8*)(xt + ((size_t)b * T_DIM + t0 + t) * F_DIM + f0 + 8*f8) = pack8(v);
        }
    } else {
        const int blockId = blockIdx.y * 32 + blockIdx.x;
        const int g0 = blockId * 256 + tid;
        const int perW = F_DIM * F_DIM / 8;
        for (int chunk = g0; chunk < 3 * perW; chunk += 65536) {
            const int wsel = chunk / perW;
            const int rem  = chunk - wsel * perW;
            const float* __restrict__ Ws = (wsel == 0) ? Wq : (wsel == 1) ? Wk : Wv;
            unsigned short* __restrict__ Wd = (wsel == 0) ? Wqb : (wsel == 1) ? Wkb : Wvb;
            float v[8];
            *(float4*)&v[0] = *(const float4*)(Ws + (size_t)rem * 8);
            *(float4*)&v[4] = *(const float4*)(Ws + (size_t)rem * 8 + 4);
            *(short8*)(Wd + (size_t)rem * 8) = pack8(v);
        }
    }
}

// ---------------- Kernel 1: merged QKV projection, BK=128 ----------------
// z<8: Q/K path (b=z>>1, which=z&1): C[t][fo], 128t x 64fo tiles, RoPE epilogue.
// z>=8: V^T path (b=z-8): A=Wv so D rows=fo, cols=t -> coalesced V^T store.
// BK=128: 4 stage phases (was 8) -> half the barriers, 32 MFMAs/wave/iter.
#define ASTR 136   // 17 16B-granules per row (odd) -> all b128 accesses conflict-free

__global__ __launch_bounds__(256, 3)
void proj_kernel(const unsigned short* __restrict__ xt,
                 const unsigned short* __restrict__ Wqb,
                 const unsigned short* __restrict__ Wkb,
                 const unsigned short* __restrict__ Wvb,
                 const float* __restrict__ bq, const float* __restrict__ bk,
                 const float* __restrict__ bv,
                 unsigned short* __restrict__ Qb, unsigned short* __restrict__ Kb,
                 unsigned short* __restrict__ Vtb)
{
    __shared__ unsigned short As[128][ASTR];
    __shared__ unsigned short Bs[64][ASTR];

    const int tid  = threadIdx.x;
    const int w    = tid >> 6;
    const int lane = tid & 63;
    const int ln15 = lane & 15;
    const int quad = lane >> 4;

    const bool is_v = (blockIdx.z >= 8);
    int t0, fo0, b;
    const unsigned short *Asrc, *Bsrc;
    if (!is_v) {
        t0  = blockIdx.x * 128;
        fo0 = blockIdx.y * 64;
        b   = blockIdx.z >> 1;
        Asrc = xt + (size_t)b * T_DIM * F_DIM + (size_t)t0 * F_DIM;
        Bsrc = ((blockIdx.z & 1) ? Wkb : Wqb) + (size_t)fo0 * F_DIM;
    } else {
        const int idx = blockIdx.y * 16 + blockIdx.x;   // 0..127
        fo0 = (idx >> 5) * 128;
        t0  = (idx & 31) * 64;
        b   = blockIdx.z - 8;
        Asrc = Wvb + (size_t)fo0 * F_DIM;
        Bsrc = xt + (size_t)b * T_DIM * F_DIM + (size_t)t0 * F_DIM;
    }

    floatx4 acc[2][4];
    #pragma unroll
    for (int mi = 0; mi < 2; ++mi)
        #pragma unroll
        for (int nt = 0; nt < 4; ++nt) acc[mi][nt] = (floatx4){0.f,0.f,0.f,0.f};

    for (int f0 = 0; f0 < F_DIM; f0 += 128) {
        __syncthreads();
        #pragma unroll
        for (int it = 0; it < 8; ++it) {          // A: 128 rows x 16 chunks
            const int idx = tid + it * 256;
            const int r = idx >> 4, c = (idx & 15) * 8;
            *(short8*)&As[r][c] = *(const short8*)(Asrc + (size_t)r * F_DIM + f0 + c);
        }
        #pragma unroll
        for (int it = 0; it < 4; ++it) {          // B: 64 rows x 16 chunks
            const int idx = tid + it * 256;
            const int r = idx >> 4, c = (idx & 15) * 8;
            *(short8*)&Bs[r][c] = *(const short8*)(Bsrc + (size_t)r * F_DIM + f0 + c);
        }
        __syncthreads();
        #pragma unroll
        for (int ks = 0; ks < 4; ++ks) {
            short8 a[2], bb[4];
            a[0] = *(const short8*)&As[w*32      + ln15][ks*32 + quad*8];
            a[1] = *(const short8*)&As[w*32 + 16 + ln15][ks*32 + quad*8];
            #pragma unroll
            for (int nt = 0; nt < 4; ++nt)
                bb[nt] = *(const short8*)&Bs[16*nt + ln15][ks*32 + quad*8];
            #pragma unroll
            for (int mi = 0; mi < 2; ++mi)
                #pragma unroll
                for (int nt = 0; nt < 4; ++nt)
                    acc[mi][nt] = __builtin_amdgcn_mfma_f32_16x16x32_bf16(
                        a[mi], bb[nt], acc[mi][nt], 0, 0, 0);
        }
    }

    if (!is_v) {
        const int which = blockIdx.z & 1;
        const float* bias = which ? bk : bq;
        unsigned short* __restrict__ Out =
            (which ? Kb : Qb) + (size_t)b * T_DIM * F_DIM;
        // Q carries 1/sqrt(F/2) * log2(e) so attn can use exp2 (v_exp_f32 native)
        const float oscale = which ? 1.0f : 0.0625f * 1.4426950408889634f;
        float bn[4];
        #pragma unroll
        for (int nt = 0; nt < 4; ++nt) bn[nt] = bias[fo0 + 16*nt + ln15];
        const float pw[2] = {
            __uint_as_float((unsigned)(123 - ln15) << 23),   // 2^-(ln15+4)
            __uint_as_float((unsigned)(107 - ln15) << 23)    // 2^-(ln15+20)
        };
        #pragma unroll
        for (int mi = 0; mi < 2; ++mi) {
            #pragma unroll
            for (int r = 0; r < 4; ++r) {
                const int t = t0 + w*32 + 16*mi + quad*4 + r;
                unsigned short* rowp = Out + (size_t)t * F_DIM + fo0;
                #pragma unroll
                for (int pr = 0; pr < 2; ++pr) {
                    const int wi = 16*pr + ln15;
                    const float re = acc[mi][pr  ][r] + bn[pr];
                    const float im = acc[mi][pr+2][r] + bn[pr+2];
                    const float u = (float)t * pw[pr];
                    float sn, cs;
                    __sincosf(u, &sn, &cs);
                    rowp[wi]      = f2bf((re * sn - im * cs) * oscale);
                    rowp[wi + 32] = f2bf((re * cs + im * sn) * oscale);
                }
            }
        }
    } else {
        #pragma unroll
        for (int mi = 0; mi < 2; ++mi) {
            #pragma unroll
            for (int r = 0; r < 4; ++r) {
                const int fo = fo0 + w*32 + 16*mi + quad*4 + r;
                const float bvv = bv[fo];
                unsigned short* rowp = Vtb + ((size_t)b * F_DIM + fo) * T_DIM + t0;
                #pragma unroll
                for (int nt = 0; nt < 4; ++nt)
                    rowp[16*nt + ln15] = f2bf(acc[mi][nt][r] + bvv);
            }
        }
    }
}

// ---------------- Kernel 2: S^T MFMA flash attention (R6 structure) --------
// no-max softmax (p = exp2(S), log2e folded into Q), split-K x2 in-block,
// 16 q-rows/wave (register sweet spot: 108 VGPRs, no spills), K+V in LDS
// (XOR swizzle, 0 conflicts), both prefetched into registers across compute.
__global__ __launch_bounds__(512, 2)
void attn_kernel(const unsigned short* __restrict__ Qb,
                 const unsigned short* __restrict__ Kb,
                 const unsigned short* __restrict__ Vtb,
                 const float* __restrict__ x,
                 const float* __restrict__ s2g,
                 float* __restrict__ out)
{
    __shared__ unsigned short smem[2][16384];   // [half][K 8192 | V 8192] = 64 KB

    const int tid  = threadIdx.x;
    const int w8   = tid >> 6;
    const int half = w8 >> 2;
    const int w    = w8 & 3;
    const int lane = tid & 63;
    const int ln15 = lane & 15;
    const int quad = lane >> 4;
    const int t256 = tid & 255;

    const int q0 = blockIdx.x * 64;
    const int h  = blockIdx.y;
    const int b  = blockIdx.z;
    const int kbase = half << 10;   // 0 or 1024

    unsigned short* __restrict__ Ks = &smem[half][0];     // 64 x 128 (perm+swizzle)
    unsigned short* __restrict__ Vs = &smem[half][8192];  // 128 x 64 (swizzle)

    const unsigned short* __restrict__ Qg =
        Qb + ((size_t)b * T_DIM + q0 + w * 16) * F_DIM + h * HF;
    const unsigned short* __restrict__ Kg =
        Kb + (size_t)b * T_DIM * F_DIM + h * HF;
    const unsigned short* __restrict__ Vg =
        Vtb + ((size_t)b * F_DIM + h * HF) * T_DIM;

    // Q B-frags (resident): B[k=feat][n=q=ln15]
    short8 qa[4];
    #pragma unroll
    for (int c = 0; c < 4; ++c)
        qa[c] = *(const short8*)(Qg + (size_t)ln15 * F_DIM + quad * 8 + 32 * c);

    floatx4 O1t[8], O2t[8];
    #pragma unroll
    for (int ft = 0; ft < 8; ++ft) {
        O1t[ft] = (floatx4){0.f, 0.f, 0.f, 0.f};
        O2t[ft] = (floatx4){0.f, 0.f, 0.f, 0.f};
    }
    float l1 = 0.f, l2 = 0.f;

    short8 kpre[4], vpre[4];
    #pragma unroll
    for (int it = 0; it < 4; ++it) {
        const int idx = t256 + it * 256;
        kpre[it] = *(const short8*)(Kg + (size_t)(kbase + (idx >> 4)) * F_DIM + (idx & 15) * 8);
    }
    #pragma unroll
    for (int it = 0; it < 4; ++it) {
        const int idx = t256 + it * 256;
        vpre[it] = *(const short8*)(Vg + (size_t)(idx >> 3) * T_DIM + kbase + (idx & 7) * 8);
    }

    for (int k0 = 0; k0 < 1024; k0 += 64) {
        __syncthreads();   // all waves done reading previous tiles
        #pragma unroll
        for (int it = 0; it < 4; ++it) {
            const int idx = t256 + it * 256;
            const int r = idx >> 4, c = idx & 15;
            // row perm so P^T C-regs align with PV B-frag slots (verified R4-R6)
            const int rp = (r & 32) | ((r & 4) << 2) | ((r & 24) >> 1) | (r & 3);
            *(short8*)&Ks[rp * 128 + (c ^ (rp & 15)) * 8] = kpre[it];
        }
        #pragma unroll
        for (int it = 0; it < 4; ++it) {
            const int idx = t256 + it * 256;
            const int r = idx >> 3, c = idx & 7;
            *(short8*)&Vs[r * 64 + (c ^ (r & 7)) * 8] = vpre[it];
        }
        __syncthreads();   // tiles visible

        if (k0 + 64 < 1024) {   // prefetch next tiles across the compute phase
            #pragma unroll
            for (int it = 0; it < 4; ++it) {
                const int idx = t256 + it * 256;
                kpre[it] = *(const short8*)(Kg + (size_t)(kbase + k0 + 64 + (idx >> 4)) * F_DIM + (idx & 15) * 8);
            }
            #pragma unroll
            for (int it = 0; it < 4; ++it) {
                const int idx = t256 + it * 256;
                vpre[it] = *(const short8*)(Vg + (size_t)(idx >> 3) * T_DIM + kbase + k0 + 64 + (idx & 7) * 8);
            }
        }

        // ---- scores S^T[k][q] ----
        floatx4 S1t[4], S2t[4];
        #pragma unroll
        for (int t = 0; t < 4; ++t) {
            const unsigned short* krow = &Ks[(16 * t + ln15) * 128];
            const short8 k0f = *(const short8*)(krow + ((quad     ) ^ ln15) * 8);
            const short8 k1f = *(const short8*)(krow + ((quad +  4) ^ ln15) * 8);
            const short8 k2f = *(const short8*)(krow + ((quad +  8) ^ ln15) * 8);
            const short8 k3f = *(const short8*)(krow + ((quad + 12) ^ ln15) * 8);
            floatx4 z = (floatx4){0.f, 0.f, 0.f, 0.f};
            floatx4 s = __builtin_amdgcn_mfma_f32_16x16x32_bf16(k0f, qa[0], z, 0, 0, 0);
            S1t[t]    = __builtin_amdgcn_mfma_f32_16x16x32_bf16(k1f, qa[1], s, 0, 0, 0);
            floatx4 u = __builtin_amdgcn_mfma_f32_16x16x32_bf16(k2f, qa[2], z, 0, 0, 0);
            S2t[t]    = __builtin_amdgcn_mfma_f32_16x16x32_bf16(k3f, qa[3], u, 0, 0, 0);
        }

        // ---- no-max softmax numerators: p = 2^S (log2e pre-folded) ----
        float e1[16], e2[16];
        #pragma unroll
        for (int t = 0; t < 4; ++t)
            #pragma unroll
            for (int r = 0; r < 4; ++r) {
                e1[4*t + r] = __builtin_amdgcn_exp2f(S1t[t][r]);
                e2[4*t + r] = __builtin_amdgcn_exp2f(S2t[t][r]);
            }
        #pragma unroll
        for (int i = 0; i < 16; ++i) { l1 += e1[i]; l2 += e2[i]; }

        short8 p1f[2], p2f[2];
        p1f[0] = pack8(&e1[0]);  p1f[1] = pack8(&e1[8]);
        p2f[0] = pack8(&e2[0]);  p2f[1] = pack8(&e2[8]);

        // ---- PV: O^T += V^T . P^T ----
        #pragma unroll
        for (int p = 0; p < 2; ++p) {
            #pragma unroll
            for (int ft = 0; ft < 8; ++ft) {
                const short8 va = *(const short8*)
                    (&Vs[(16*ft + ln15) * 64 + (((4*p + quad) ^ (ln15 & 7))) * 8]);
                O1t[ft] = __builtin_amdgcn_mfma_f32_16x16x32_bf16(va, p1f[p], O1t[ft], 0, 0, 0);
                O2t[ft] = __builtin_amdgcn_mfma_f32_16x16x32_bf16(va, p2f[p], O2t[ft], 0, 0, 0);
            }
        }
    }

    // ---- reductions: intra-wave l across quads, then cross-half via LDS ----
    l1 += __shfl_xor(l1, 16); l1 += __shfl_xor(l1, 32);
    l2 += __shfl_xor(l2, 16); l2 += __shfl_xor(l2, 32);

    float* comb = (float*)&smem[0][0];
    __syncthreads();   // all compute done, smem reusable
    if (half == 1) {
        if (quad == 0) { comb[w*16 + ln15] = l1; comb[64 + w*16 + ln15] = l2; }
        #pragma unroll
        for (int ft = 0; ft < 8; ++ft)
            #pragma unroll
            for (int r = 0; r < 4; ++r)
                comb[128 + (ft*4 + r) * 256 + w*64 + lane] = O1t[ft][r];
    }
    __syncthreads();
    if (half == 0) {
        l1 += comb[w*16 + ln15];
        l2 += comb[64 + w*16 + ln15];
        #pragma unroll
        for (int ft = 0; ft < 8; ++ft)
            #pragma unroll
            for (int r = 0; r < 4; ++r)
                O1t[ft][r] += comb[128 + (ft*4 + r) * 256 + w*64 + lane];
    }
    __syncthreads();
    if (half == 1) {
        #pragma unroll
        for (int ft = 0; ft < 8; ++ft)
            #pragma unroll
            for (int r = 0; r < 4; ++r)
                comb[128 + (ft*4 + r) * 256 + w*64 + lane] = O2t[ft][r];
    }
    __syncthreads();
    if (half == 0) {
        #pragma unroll
        for (int ft = 0; ft < 8; ++ft)
            #pragma unroll
            for (int r = 0; r < 4; ++r)
                O2t[ft][r] += comb[128 + (ft*4 + r) * 256 + w*64 + lane];

        // ---- epilogue: out = x + O1/l1 - s2*O2/l2, layout [B][F][T] ----
        const float s2h = s2g[h];
        const float i1 = 1.f / l1;
        const float i2 = s2h / l2;
        const size_t obase = (size_t)b * F_DIM * T_DIM;
        const int f0 = h * HF;
        const int t = q0 + w * 16 + ln15;
        #pragma unroll
        for (int ft = 0; ft < 8; ++ft) {
            #pragma unroll
            for (int r = 0; r < 4; ++r) {
                const int feat = 16*ft + 4*quad + r;
                const size_t idx = obase + (size_t)(f0 + feat) * T_DIM + t;
                out[idx] = x[idx] + O1t[ft][r] * i1 - O2t[ft][r] * i2;
            }
        }
    }
}

extern "C" void kernel_launch(void* const* d_in, const int* in_sizes, int n_in,
                              void* d_out, int out_size, void* d_ws, size_t ws_size,
                              hipStream_t stream)
{
    const float* x  = (const float*)d_in[0];
    const float* Wq = (const float*)d_in[1];
    const float* bq = (const float*)d_in[2];
    const float* Wk = (const float*)d_in[3];
    const float* bk = (const float*)d_in[4];
    const float* Wv = (const float*)d_in[5];
    const float* bv = (const float*)d_in[6];
    const float* s2 = (const float*)d_in[7];
    float* out = (float*)d_out;

    const size_t per = (size_t)B_DIM * T_DIM * F_DIM;
    const size_t wsz = (size_t)F_DIM * F_DIM;
    unsigned short* xt  = (unsigned short*)d_ws;
    unsigned short* Wqb = xt + per;
    unsigned short* Wkb = Wqb + wsz;
    unsigned short* Wvb = Wkb + wsz;
    unsigned short* Qb  = Wvb + wsz;
    unsigned short* Kb  = Qb + per;
    unsigned short* Vtb = Kb + per;

    hipLaunchKernelGGL(prep_kernel, dim3(32, 8, 5), dim3(256), 0, stream,
                       x, Wq, Wk, Wv, xt, Wqb, Wkb, Wvb);

    hipLaunchKernelGGL(proj_kernel, dim3(16, 8, 12), dim3(256), 0, stream,
                       xt, Wqb, Wkb, Wvb, bq, bk, bv, Qb, Kb, Vtb);

    hipLaunchKernelGGL(attn_kernel, dim3(32, 4, 4), dim3(512), 0, stream,
                       Qb, Kb, Vtb, x, s2, out);
}